// Round 4
// baseline (308.457 us; speedup 1.0000x reference)
//
#include <hip/hip_runtime.h>
#include <hip/hip_bf16.h>

typedef __attribute__((ext_vector_type(8))) short short8;
typedef __attribute__((ext_vector_type(4))) float f32x4;
typedef __attribute__((ext_vector_type(4))) unsigned short us4;

static __device__ __forceinline__ unsigned short f2bf(float f) {
    union { float f; unsigned u; } v; v.f = f;
    unsigned r = (v.u + 0x7FFFu + ((v.u >> 16) & 1u)) >> 16;
    return (unsigned short)r;
}
// pack two f32 -> bf16x2 dword, round-to-nearest-even
static __device__ __forceinline__ unsigned pk2(float a, float b) {
    union { float f; unsigned u; } x, y; x.f = a; y.f = b;
    unsigned lo = (x.u + 0x7FFFu + ((x.u >> 16) & 1u)) >> 16;
    unsigned hi = (y.u + 0x7FFFu + ((y.u >> 16) & 1u)) >> 16;
    return lo | (hi << 16);
}
// fast pack (round-up-at-half), for P only
static __device__ __forceinline__ unsigned pk2f(float a, float b) {
    union { float f; unsigned u; } x, y; x.f = a; y.f = b;
    return ((x.u + 0x8000u) >> 16) | ((y.u + 0x8000u) & 0xFFFF0000u);
}

#if __has_builtin(__builtin_amdgcn_exp2f)
#define EXP2(x) __builtin_amdgcn_exp2f(x)
#else
#define EXP2(x) exp2f(x)
#endif

static __device__ __forceinline__ void gld16(const unsigned short* g, unsigned short* l) {
    __builtin_amdgcn_global_load_lds(
        (const __attribute__((address_space(1))) void*)g,
        (__attribute__((address_space(3))) void*)l, 16, 0, 0);
}

// scale * log2(e), folded into Q at projection time
#define QSCALE (0.125f * 1.44269504f)

// ---------------- convert: fp32 -> bf16 staging ----------------
__global__ __launch_bounds__(256) void convert_all(
    const float* __restrict__ x,  const float* __restrict__ wq,
    const float* __restrict__ wk, const float* __restrict__ wv,
    const float* __restrict__ wo, const float* __restrict__ bq,
    const float* __restrict__ bk, const float* __restrict__ bv,
    unsigned short* __restrict__ xbf, unsigned short* __restrict__ wqkv,
    unsigned short* __restrict__ wobf, float* __restrict__ bqkv)
{
    const int NX4 = (4096 * 1024) / 4;   // 1048576
    const int NW4 = (1024 * 1024) / 4;   // 262144
    int i = blockIdx.x * 256 + threadIdx.x;
    if (i < NX4) {
        float4 v = ((const float4*)x)[i];
        us4 o = { f2bf(v.x), f2bf(v.y), f2bf(v.z), f2bf(v.w) };
        ((us4*)xbf)[i] = o;
    } else if (i < NX4 + 3 * NW4) {
        int j = i - NX4;
        const float* src = (j < NW4) ? wq + 4 * j
                         : (j < 2 * NW4) ? wk + 4 * (j - NW4)
                         : wv + 4 * (j - 2 * NW4);
        float4 v = *(const float4*)src;
        us4 o = { f2bf(v.x), f2bf(v.y), f2bf(v.z), f2bf(v.w) };
        ((us4*)wqkv)[j] = o;
    } else if (i < NX4 + 4 * NW4) {
        int j = i - NX4 - 3 * NW4;
        float4 v = ((const float4*)wo)[j];
        us4 o = { f2bf(v.x), f2bf(v.y), f2bf(v.z), f2bf(v.w) };
        ((us4*)wobf)[j] = o;
    } else if (i < NX4 + 4 * NW4 + 768) {
        int j = i - NX4 - 4 * NW4;
        const float* src = (j < 256) ? bq + 4 * j
                         : (j < 512) ? bk + 4 * (j - 256)
                         : bv + 4 * (j - 512);
        ((float4*)bqkv)[j] = *(const float4*)src;
    }
}

// ---------------- GEMM  C = A * B^T (+bias), bf16 MFMA --------------------
// Double-buffered gld16 staging: prefetch tile kt+1 before computing kt, so
// the vmcnt(0) drain at the barrier overlaps the MFMA+LDS compute phase.
// LDS layout per buffer: [k8chunk 0..7][row 0..BM/BN][8 shorts] (conflict-free)
// MODE 0: A = xbf [4096x1024]; epilogue -> Qb [bh][n][64] (pre-scaled),
//         Kb = K8 [bh][d8][n][8], Vtb = V8 [bh][n8][d][8]
// MODE 1: A = Ob [bh][n][64] head-gathered; epilogue -> fp32 out
template <int MODE, int BM, int BN, int WR, int WC>
__global__ __launch_bounds__(256) void gemm_bt(
    const unsigned short* __restrict__ A, const unsigned short* __restrict__ B,
    const float* __restrict__ bias,
    unsigned short* __restrict__ Qb, unsigned short* __restrict__ Kb,
    unsigned short* __restrict__ Vtb, float* __restrict__ Cout, int Mtiles)
{
    constexpr int WM = BM / WR, WN = BN / WC;
    constexpr int IT = WM / 16, JT = WN / 16;
    constexpr int ASZ = BM * 64, BSZ = BN * 64;   // shorts per buffer
    __shared__ __attribute__((aligned(16))) unsigned short As[2 * ASZ];
    __shared__ __attribute__((aligned(16))) unsigned short Bs[2 * BSZ];
    const int tid = threadIdx.x, lane = tid & 63, wave = tid >> 6;
    const int bm = blockIdx.x % Mtiles, bn = blockIdx.x / Mtiles;
    const int m0 = bm * BM, n0 = bn * BN;
    const int wr = wave / WC, wc = wave % WC;
    const int lo = lane & 15, g = lane >> 4;

    f32x4 acc[IT][JT];
#pragma unroll
    for (int i = 0; i < IT; ++i)
#pragma unroll
        for (int j = 0; j < JT; ++j) acc[i][j] = (f32x4){0.f, 0.f, 0.f, 0.f};

    auto stage = [&](int kt, int buf) {
        const int k0 = kt * 64;
#pragma unroll
        for (int p = 0; p < BM / 32; ++p) {
            int off = p * 2048 + tid * 8;
            int k8l = off / (BM * 8), m = (off >> 3) & (BM - 1);
            const unsigned short* srcA;
            if (MODE == 0) {
                srcA = A + (size_t)(m0 + m) * 1024 + k0 + k8l * 8;
            } else {
                int gr = m0 + m, b = gr >> 11, n = gr & 2047;
                srcA = A + ((size_t)((b << 4) + kt) * 2048 + n) * 64 + k8l * 8;
            }
            gld16(srcA, &As[buf * ASZ + off]);
        }
#pragma unroll
        for (int p = 0; p < BN / 32; ++p) {
            int off = p * 2048 + tid * 8;
            int k8l = off / (BN * 8), m = (off >> 3) & (BN - 1);
            gld16(B + (size_t)(n0 + m) * 1024 + k0 + k8l * 8, &Bs[buf * BSZ + off]);
        }
    };

    stage(0, 0);
    __syncthreads();
    for (int kt = 0; kt < 16; ++kt) {
        const int cur = kt & 1;
        if (kt < 15) stage(kt + 1, cur ^ 1);   // async prefetch, drained at barrier
        short8 af[IT][2], bf[JT][2];
#pragma unroll
        for (int kc = 0; kc < 2; ++kc) {
#pragma unroll
            for (int i = 0; i < IT; ++i)
                af[i][kc] = *(const short8*)&As[cur * ASZ +
                    ((kc * 4 + g) * BM + wr * WM + i * 16 + lo) * 8];
#pragma unroll
            for (int j = 0; j < JT; ++j)
                bf[j][kc] = *(const short8*)&Bs[cur * BSZ +
                    ((kc * 4 + g) * BN + wc * WN + j * 16 + lo) * 8];
        }
#pragma unroll
        for (int kc = 0; kc < 2; ++kc)
#pragma unroll
            for (int i = 0; i < IT; ++i)
#pragma unroll
                for (int j = 0; j < JT; ++j)
                    acc[i][j] = __builtin_amdgcn_mfma_f32_16x16x32_bf16(
                        af[i][kc], bf[j][kc], acc[i][j], 0, 0, 0);
        __syncthreads();
    }

    if (MODE == 0) {
        const int sect = n0 >> 10;   // uniform per block: 0=Q, 1=K, 2=V
#pragma unroll
        for (int i = 0; i < IT; ++i)
#pragma unroll
            for (int j = 0; j < JT; ++j) {
                int gc = n0 + wc * WN + j * 16 + lo;
                int d = gc & 1023, h = d >> 6, hd = d & 63;
                float bv = bias[gc];
                int nb = m0 + wr * WM + i * 16 + g * 4;
                int b = nb >> 11, n = nb & 2047;
                size_t hb = (size_t)((b << 4) + h) * 131072;
                if (sect == 0) {
#pragma unroll
                    for (int r = 0; r < 4; ++r)
                        Qb[hb + (size_t)(n + r) * 64 + hd] =
                            f2bf((acc[i][j][r] + bv) * QSCALE);
                } else if (sect == 1) {
#pragma unroll
                    for (int r = 0; r < 4; ++r)
                        Kb[hb + (size_t)(hd >> 3) * 16384 + (size_t)(n + r) * 8 + (hd & 7)] =
                            f2bf(acc[i][j][r] + bv);
                } else {
                    uint2 w;
                    w.x = pk2(acc[i][j][0] + bv, acc[i][j][1] + bv);
                    w.y = pk2(acc[i][j][2] + bv, acc[i][j][3] + bv);
                    *(uint2*)&Vtb[hb + (size_t)(n >> 3) * 512 + (size_t)hd * 8 + (n & 7)] = w;
                }
            }
    } else {
#pragma unroll
        for (int i = 0; i < IT; ++i)
#pragma unroll
            for (int j = 0; j < JT; ++j)
#pragma unroll
                for (int r = 0; r < 4; ++r) {
                    int gr = m0 + wr * WM + i * 16 + g * 4 + r;
                    int gc = n0 + wc * WN + j * 16 + lo;
                    Cout[(size_t)gr * 1024 + gc] = acc[i][j][r] + bias[gc];
                }
    }
}

// ---------------- flash attention, barrier-free ---------------------------
// K/V fragments load straight from global (chunked layouts make each frag a
// contiguous 16-B per-lane load); LDS only for per-wave P transpose -> zero
// __syncthreads. Grid is qt-major so one head's 16 q-tiles share an XCD L2.
// grid: 16 qt * 32 bh = 512 blocks, 256 threads (4 waves x 32 q-rows)
__global__ __launch_bounds__(256) void attn_kernel(
    const unsigned short* __restrict__ Qb, const unsigned short* __restrict__ Kb,
    const unsigned short* __restrict__ Vtb, unsigned short* __restrict__ Ob)
{
    __shared__ __attribute__((aligned(16))) unsigned short PT[4 * 32 * 136];
    const int tid = threadIdx.x, lane = tid & 63, wave = tid >> 6;
    const int lo = lane & 15, g = lane >> 4;
    const int bh = blockIdx.x & 31, qt = blockIdx.x >> 5;   // qt-major
    const size_t base = (size_t)bh * 131072;
    const int q0w = qt * 128 + wave * 32;

    short8 aq[2][2];
#pragma unroll
    for (int rb = 0; rb < 2; ++rb) {
        const unsigned short* qp = Qb + base + (size_t)(q0w + rb * 16 + lo) * 64 + g * 8;
        aq[rb][0] = *(const short8*)qp;
        aq[rb][1] = *(const short8*)(qp + 32);
    }
    f32x4 o[2][4];
    float l[2] = {0.f, 0.f};
#pragma unroll
    for (int rb = 0; rb < 2; ++rb)
#pragma unroll
        for (int c = 0; c < 4; ++c) o[rb][c] = (f32x4){0.f, 0.f, 0.f, 0.f};
    unsigned short* myP = PT + wave * (32 * 136);
    const unsigned short* Kg = Kb + base;    // [d8][n 2048][8]
    const unsigned short* Vg = Vtb + base;   // [n8 256][d 64][8]

    for (int kt = 0; kt < 16; ++kt) {
        const int k0 = kt * 128;
        // ---- S^T = K * Q^T (k in regs, q in lanes), exp2, store P^T ----
#pragma unroll
        for (int ct = 0; ct < 8; ++ct) {
            const unsigned short* kp = Kg + (size_t)(k0 + ct * 16 + lo) * 8;
            short8 kf0 = *(const short8*)(kp + (size_t)g * 16384);
            short8 kf1 = *(const short8*)(kp + (size_t)(4 + g) * 16384);
#pragma unroll
            for (int rb = 0; rb < 2; ++rb) {
                f32x4 z = (f32x4){0.f, 0.f, 0.f, 0.f};
                f32x4 s = __builtin_amdgcn_mfma_f32_16x16x32_bf16(kf0, aq[rb][0], z, 0, 0, 0);
                s = __builtin_amdgcn_mfma_f32_16x16x32_bf16(kf1, aq[rb][1], s, 0, 0, 0);
                float p0 = EXP2(s[0]), p1 = EXP2(s[1]);
                float p2 = EXP2(s[2]), p3 = EXP2(s[3]);
                l[rb] += (p0 + p1) + (p2 + p3);
                uint2 w; w.x = pk2f(p0, p1); w.y = pk2f(p2, p3);
                *(uint2*)&myP[(rb * 16 + lo) * 136 + ct * 16 + g * 4] = w;
            }
        }
        // ---- O^T += V^T * P^T ----
#pragma unroll
        for (int kc = 0; kc < 4; ++kc) {
            short8 bp0 = *(const short8*)&myP[lo * 136 + kc * 32 + g * 8];
            short8 bp1 = *(const short8*)&myP[(16 + lo) * 136 + kc * 32 + g * 8];
#pragma unroll
            for (int c = 0; c < 4; ++c) {
                short8 vf = *(const short8*)(Vg +
                    (size_t)((k0 >> 3) + kc * 4 + g) * 512 + (size_t)(c * 16 + lo) * 8);
                o[0][c] = __builtin_amdgcn_mfma_f32_16x16x32_bf16(vf, bp0, o[0][c], 0, 0, 0);
                o[1][c] = __builtin_amdgcn_mfma_f32_16x16x32_bf16(vf, bp1, o[1][c], 0, 0, 0);
            }
        }
    }

    float inv[2];
#pragma unroll
    for (int rb = 0; rb < 2; ++rb) {
        float v = l[rb];
        v += __shfl_xor(v, 16);
        v += __shfl_xor(v, 32);
        inv[rb] = 1.f / v;
    }
#pragma unroll
    for (int rb = 0; rb < 2; ++rb)
#pragma unroll
        for (int c = 0; c < 4; ++c) {
            uint2 w;
            w.x = pk2(o[rb][c][0] * inv[rb], o[rb][c][1] * inv[rb]);
            w.y = pk2(o[rb][c][2] * inv[rb], o[rb][c][3] * inv[rb]);
            *(uint2*)&Ob[base + (size_t)(q0w + rb * 16 + lo) * 64 + c * 16 + g * 4] = w;
        }
}

// ---------------- launcher ----------------
extern "C" void kernel_launch(void* const* d_in, const int* in_sizes, int n_in,
                              void* d_out, int out_size, void* d_ws, size_t ws_size,
                              hipStream_t stream) {
    const float* x  = (const float*)d_in[0];
    const float* Wq = (const float*)d_in[1];
    const float* bq = (const float*)d_in[2];
    const float* Wk = (const float*)d_in[3];
    const float* bk = (const float*)d_in[4];
    const float* Wv = (const float*)d_in[5];
    const float* bv = (const float*)d_in[6];
    const float* Wo = (const float*)d_in[7];
    const float* bo = (const float*)d_in[8];
    float* out = (float*)d_out;

    char* ws = (char*)d_ws;
    unsigned short* xbf  = (unsigned short*)ws;
    unsigned short* wqkv = (unsigned short*)(ws + 8388608);
    unsigned short* wobf = (unsigned short*)(ws + 14680064);
    float*          bqkv = (float*)(ws + 16777216);
    unsigned short* Qb   = (unsigned short*)(ws + 16789504);
    unsigned short* Kb   = (unsigned short*)(ws + 16789504 + 8388608);
    unsigned short* Vtb  = (unsigned short*)(ws + 16789504 + 2 * 8388608);
    unsigned short* Ob   = (unsigned short*)(ws + 16789504 + 3 * 8388608);

    convert_all<<<8195, 256, 0, stream>>>(x, Wq, Wk, Wv, Wo, bq, bk, bv,
                                          xbf, wqkv, wobf, bqkv);
    gemm_bt<0, 128, 128, 2, 2><<<32 * 24, 256, 0, stream>>>(
        xbf, wqkv, bqkv, Qb, Kb, Vtb, nullptr, 32);
    attn_kernel<<<512, 256, 0, stream>>>(Qb, Kb, Vtb, Ob);
    gemm_bt<1, 64, 128, 1, 4><<<64 * 8, 256, 0, stream>>>(
        Ob, wobf, bo, nullptr, nullptr, nullptr, out, 64);
}

// Round 5
// 232.315 us; speedup vs baseline: 1.3278x; 1.3278x over previous
//
#include <hip/hip_runtime.h>
#include <hip/hip_bf16.h>

typedef __attribute__((ext_vector_type(8))) short short8;
typedef __attribute__((ext_vector_type(4))) float f32x4;
typedef __attribute__((ext_vector_type(4))) unsigned short us4;

static __device__ __forceinline__ unsigned short f2bf(float f) {
    union { float f; unsigned u; } v; v.f = f;
    unsigned r = (v.u + 0x7FFFu + ((v.u >> 16) & 1u)) >> 16;
    return (unsigned short)r;
}
// pack two f32 -> bf16x2 dword, round-to-nearest-even
static __device__ __forceinline__ unsigned pk2(float a, float b) {
    union { float f; unsigned u; } x, y; x.f = a; y.f = b;
    unsigned lo = (x.u + 0x7FFFu + ((x.u >> 16) & 1u)) >> 16;
    unsigned hi = (y.u + 0x7FFFu + ((y.u >> 16) & 1u)) >> 16;
    return lo | (hi << 16);
}
// fast pack (round-up-at-half), for P only
static __device__ __forceinline__ unsigned pk2f(float a, float b) {
    union { float f; unsigned u; } x, y; x.f = a; y.f = b;
    return ((x.u + 0x8000u) >> 16) | ((y.u + 0x8000u) & 0xFFFF0000u);
}

#if __has_builtin(__builtin_amdgcn_exp2f)
#define EXP2(x) __builtin_amdgcn_exp2f(x)
#else
#define EXP2(x) exp2f(x)
#endif

static __device__ __forceinline__ void gld16(const unsigned short* g, unsigned short* l) {
    __builtin_amdgcn_global_load_lds(
        (const __attribute__((address_space(1))) void*)g,
        (__attribute__((address_space(3))) void*)l, 16, 0, 0);
}

// scale * log2(e), folded into Q at projection time
#define QSCALE (0.125f * 1.44269504f)

// ---------------- convert: fp32 -> bf16 staging ----------------
__global__ __launch_bounds__(256) void convert_all(
    const float* __restrict__ x,  const float* __restrict__ wq,
    const float* __restrict__ wk, const float* __restrict__ wv,
    const float* __restrict__ wo, const float* __restrict__ bq,
    const float* __restrict__ bk, const float* __restrict__ bv,
    unsigned short* __restrict__ xbf, unsigned short* __restrict__ wqkv,
    unsigned short* __restrict__ wobf, float* __restrict__ bqkv)
{
    const int NX4 = (4096 * 1024) / 4;   // 1048576
    const int NW4 = (1024 * 1024) / 4;   // 262144
    int i = blockIdx.x * 256 + threadIdx.x;
    if (i < NX4) {
        float4 v = ((const float4*)x)[i];
        us4 o = { f2bf(v.x), f2bf(v.y), f2bf(v.z), f2bf(v.w) };
        ((us4*)xbf)[i] = o;
    } else if (i < NX4 + 3 * NW4) {
        int j = i - NX4;
        const float* src = (j < NW4) ? wq + 4 * j
                         : (j < 2 * NW4) ? wk + 4 * (j - NW4)
                         : wv + 4 * (j - 2 * NW4);
        float4 v = *(const float4*)src;
        us4 o = { f2bf(v.x), f2bf(v.y), f2bf(v.z), f2bf(v.w) };
        ((us4*)wqkv)[j] = o;
    } else if (i < NX4 + 4 * NW4) {
        int j = i - NX4 - 3 * NW4;
        float4 v = ((const float4*)wo)[j];
        us4 o = { f2bf(v.x), f2bf(v.y), f2bf(v.z), f2bf(v.w) };
        ((us4*)wobf)[j] = o;
    } else if (i < NX4 + 4 * NW4 + 768) {
        int j = i - NX4 - 4 * NW4;
        const float* src = (j < 256) ? bq + 4 * j
                         : (j < 512) ? bk + 4 * (j - 256)
                         : bv + 4 * (j - 512);
        ((float4*)bqkv)[j] = *(const float4*)src;
    }
}

// ---------------- GEMM  C = A * B^T (+bias), bf16 MFMA, gld16 staging ----
// Single-buffered (round-3 structure: best measured). LDS layout per tile:
// [k8chunk][row][8 shorts] -> conflict-free fragment reads.
// MODE 0: A = xbf [4096x1024]; epilogue -> Qb [bh][n][64] (pre-scaled),
//         Kb = K8 [bh][d8][n][8], Vtb = V8 [bh][n8][d][8]
// MODE 1: A = Ob [bh][n][64] head-gathered; epilogue -> fp32 out
template <int MODE, int BM, int BN, int WR, int WC>
__global__ __launch_bounds__(256) void gemm_bt(
    const unsigned short* __restrict__ A, const unsigned short* __restrict__ B,
    const float* __restrict__ bias,
    unsigned short* __restrict__ Qb, unsigned short* __restrict__ Kb,
    unsigned short* __restrict__ Vtb, float* __restrict__ Cout, int Mtiles)
{
    constexpr int WM = BM / WR, WN = BN / WC;
    constexpr int IT = WM / 16, JT = WN / 16;
    __shared__ __attribute__((aligned(16))) unsigned short As[BM * 64];
    __shared__ __attribute__((aligned(16))) unsigned short Bs[BN * 64];
    const int tid = threadIdx.x, lane = tid & 63;
    const int wave = tid >> 6;
    const int bm = blockIdx.x % Mtiles, bn = blockIdx.x / Mtiles;
    const int m0 = bm * BM, n0 = bn * BN;
    const int wr = wave / WC, wc = wave % WC;
    const int lo = lane & 15, g = lane >> 4;

    f32x4 acc[IT][JT];
#pragma unroll
    for (int i = 0; i < IT; ++i)
#pragma unroll
        for (int j = 0; j < JT; ++j) acc[i][j] = (f32x4){0.f, 0.f, 0.f, 0.f};

    for (int kt = 0; kt < 16; ++kt) {
        const int k0 = kt * 64;
#pragma unroll
        for (int p = 0; p < BM / 32; ++p) {
            int off = p * 2048 + tid * 8;
            int k8l = off / (BM * 8), m = (off >> 3) & (BM - 1);
            const unsigned short* srcA;
            if (MODE == 0) {
                srcA = A + (size_t)(m0 + m) * 1024 + k0 + k8l * 8;
            } else {
                int gr = m0 + m, b = gr >> 11, n = gr & 2047;
                srcA = A + ((size_t)((b << 4) + kt) * 2048 + n) * 64 + k8l * 8;
            }
            gld16(srcA, &As[off]);
        }
#pragma unroll
        for (int p = 0; p < BN / 32; ++p) {
            int off = p * 2048 + tid * 8;
            int k8l = off / (BN * 8), m = (off >> 3) & (BN - 1);
            gld16(B + (size_t)(n0 + m) * 1024 + k0 + k8l * 8, &Bs[off]);
        }
        __syncthreads();
        short8 af[IT][2], bf[JT][2];
#pragma unroll
        for (int kc = 0; kc < 2; ++kc) {
#pragma unroll
            for (int i = 0; i < IT; ++i)
                af[i][kc] = *(const short8*)&As[((kc * 4 + g) * BM + wr * WM + i * 16 + lo) * 8];
#pragma unroll
            for (int j = 0; j < JT; ++j)
                bf[j][kc] = *(const short8*)&Bs[((kc * 4 + g) * BN + wc * WN + j * 16 + lo) * 8];
        }
#pragma unroll
        for (int kc = 0; kc < 2; ++kc)
#pragma unroll
            for (int i = 0; i < IT; ++i)
#pragma unroll
                for (int j = 0; j < JT; ++j)
                    acc[i][j] = __builtin_amdgcn_mfma_f32_16x16x32_bf16(
                        af[i][kc], bf[j][kc], acc[i][j], 0, 0, 0);
        __syncthreads();
    }

    if (MODE == 0) {
        const int sect = n0 >> 10;   // uniform per block: 0=Q, 1=K, 2=V
#pragma unroll
        for (int i = 0; i < IT; ++i)
#pragma unroll
            for (int j = 0; j < JT; ++j) {
                int gc = n0 + wc * WN + j * 16 + lo;
                int d = gc & 1023, h = d >> 6, hd = d & 63;
                float bv = bias[gc];
                int nb = m0 + wr * WM + i * 16 + g * 4;
                int b = nb >> 11, n = nb & 2047;
                size_t hb = (size_t)((b << 4) + h) * 131072;
                if (sect == 0) {
#pragma unroll
                    for (int r = 0; r < 4; ++r)
                        Qb[hb + (size_t)(n + r) * 64 + hd] =
                            f2bf((acc[i][j][r] + bv) * QSCALE);
                } else if (sect == 1) {
#pragma unroll
                    for (int r = 0; r < 4; ++r)
                        Kb[hb + (size_t)(hd >> 3) * 16384 + (size_t)(n + r) * 8 + (hd & 7)] =
                            f2bf(acc[i][j][r] + bv);
                } else {
                    uint2 w;
                    w.x = pk2(acc[i][j][0] + bv, acc[i][j][1] + bv);
                    w.y = pk2(acc[i][j][2] + bv, acc[i][j][3] + bv);
                    *(uint2*)&Vtb[hb + (size_t)(n >> 3) * 512 + (size_t)hd * 8 + (n & 7)] = w;
                }
            }
    } else {
#pragma unroll
        for (int i = 0; i < IT; ++i)
#pragma unroll
            for (int j = 0; j < JT; ++j)
#pragma unroll
                for (int r = 0; r < 4; ++r) {
                    int gr = m0 + wr * WM + i * 16 + g * 4 + r;
                    int gc = n0 + wc * WN + j * 16 + lo;
                    Cout[(size_t)gr * 1024 + gc] = acc[i][j][r] + bias[gc];
                }
    }
}

// ---------------- flash attention, register-pipelined, barrier-free ------
// 64-key steps; K/V fragments loaded straight from global (chunked layouts:
// Kb [bh][d8][n][8], Vtb [bh][n8][d][8]) into double-buffered register
// arrays, prefetched one step ahead (~400 cyc distance >> L2 latency; the
// 16 KB tile is shared by all 4 waves via L1). LDS holds only the per-wave
// P^T transpose -> zero __syncthreads in the whole kernel.
// grid: 16 qt * 32 bh = 512 blocks qt-major, 256 threads (4 waves x 32 q)
__global__ __launch_bounds__(256, 2) void attn_kernel(
    const unsigned short* __restrict__ Qb, const unsigned short* __restrict__ Kb,
    const unsigned short* __restrict__ Vtb, unsigned short* __restrict__ Ob)
{
    __shared__ __attribute__((aligned(16))) unsigned short PT[4 * 32 * 72];
    const int tid = threadIdx.x, lane = tid & 63, wave = tid >> 6;
    const int lo = lane & 15, g = lane >> 4;
    const int bh = blockIdx.x & 31, qt = blockIdx.x >> 5;   // qt-major
    const size_t base = (size_t)bh * 131072;
    const int q0w = qt * 128 + wave * 32;

    short8 aq[2][2];
#pragma unroll
    for (int rb = 0; rb < 2; ++rb) {
        const unsigned short* qp = Qb + base + (size_t)(q0w + rb * 16 + lo) * 64 + g * 8;
        aq[rb][0] = *(const short8*)qp;
        aq[rb][1] = *(const short8*)(qp + 32);
    }
    f32x4 o[2][4];
    float l[2] = {0.f, 0.f};
#pragma unroll
    for (int rb = 0; rb < 2; ++rb)
#pragma unroll
        for (int c = 0; c < 4; ++c) o[rb][c] = (f32x4){0.f, 0.f, 0.f, 0.f};
    unsigned short* myP = PT + wave * (32 * 72);

    // per-lane base pointers
    const unsigned short* kb0 = Kb + base + (size_t)g * 16384 + (size_t)lo * 8;       // d 0..31
    const unsigned short* kb1 = kb0 + 4 * 16384;                                      // d 32..63
    const unsigned short* vb  = Vtb + base + (size_t)g * 512 + (size_t)lo * 8;

    short8 kf[2][8], vf[2][8];
    auto loadK = [&](int kt, short8* f) {
        const unsigned short* p0 = kb0 + kt * 512;   // 64 keys * 8
        const unsigned short* p1 = kb1 + kt * 512;
#pragma unroll
        for (int ct = 0; ct < 4; ++ct) {
            f[2 * ct]     = *(const short8*)(p0 + ct * 128);
            f[2 * ct + 1] = *(const short8*)(p1 + ct * 128);
        }
    };
    auto loadV = [&](int kt, short8* f) {
        const unsigned short* p = vb + (size_t)kt * 4096;   // 8 n8-rows * 512
#pragma unroll
        for (int kc2 = 0; kc2 < 2; ++kc2)
#pragma unroll
            for (int c = 0; c < 4; ++c)
                f[kc2 * 4 + c] = *(const short8*)(p + kc2 * 2048 + c * 128);
    };

    loadK(0, kf[0]);
    loadV(0, vf[0]);

#pragma unroll 2
    for (int kt = 0; kt < 32; ++kt) {
        const int cur = kt & 1, nxt = cur ^ 1;
        const int ktn = (kt < 31) ? kt + 1 : 31;    // clamped (branch-free prefetch)
        loadK(ktn, kf[nxt]);
        // ---- S^T = K * Q^T (keys in rows, q in lanes), exp2, store P^T ----
#pragma unroll
        for (int ct = 0; ct < 4; ++ct) {
#pragma unroll
            for (int rb = 0; rb < 2; ++rb) {
                f32x4 z = (f32x4){0.f, 0.f, 0.f, 0.f};
                f32x4 s = __builtin_amdgcn_mfma_f32_16x16x32_bf16(kf[cur][2 * ct], aq[rb][0], z, 0, 0, 0);
                s = __builtin_amdgcn_mfma_f32_16x16x32_bf16(kf[cur][2 * ct + 1], aq[rb][1], s, 0, 0, 0);
                float p0 = EXP2(s[0]), p1 = EXP2(s[1]);
                float p2 = EXP2(s[2]), p3 = EXP2(s[3]);
                l[rb] += (p0 + p1) + (p2 + p3);
                uint2 w; w.x = pk2f(p0, p1); w.y = pk2f(p2, p3);
                *(uint2*)&myP[(rb * 16 + lo) * 72 + ct * 16 + g * 4] = w;
            }
        }
        loadV(ktn, vf[nxt]);
        // ---- O^T += V^T * P^T ----
#pragma unroll
        for (int kc2 = 0; kc2 < 2; ++kc2) {
            short8 bp0 = *(const short8*)&myP[lo * 72 + kc2 * 32 + g * 8];
            short8 bp1 = *(const short8*)&myP[(16 + lo) * 72 + kc2 * 32 + g * 8];
#pragma unroll
            for (int c = 0; c < 4; ++c) {
                short8 v8 = vf[cur][kc2 * 4 + c];
                o[0][c] = __builtin_amdgcn_mfma_f32_16x16x32_bf16(v8, bp0, o[0][c], 0, 0, 0);
                o[1][c] = __builtin_amdgcn_mfma_f32_16x16x32_bf16(v8, bp1, o[1][c], 0, 0, 0);
            }
        }
    }

    float inv[2];
#pragma unroll
    for (int rb = 0; rb < 2; ++rb) {
        float v = l[rb];
        v += __shfl_xor(v, 16);
        v += __shfl_xor(v, 32);
        inv[rb] = 1.f / v;
    }
#pragma unroll
    for (int rb = 0; rb < 2; ++rb)
#pragma unroll
        for (int c = 0; c < 4; ++c) {
            uint2 w;
            w.x = pk2(o[rb][c][0] * inv[rb], o[rb][c][1] * inv[rb]);
            w.y = pk2(o[rb][c][2] * inv[rb], o[rb][c][3] * inv[rb]);
            *(uint2*)&Ob[base + (size_t)(q0w + rb * 16 + lo) * 64 + c * 16 + g * 4] = w;
        }
}

// ---------------- launcher ----------------
extern "C" void kernel_launch(void* const* d_in, const int* in_sizes, int n_in,
                              void* d_out, int out_size, void* d_ws, size_t ws_size,
                              hipStream_t stream) {
    const float* x  = (const float*)d_in[0];
    const float* Wq = (const float*)d_in[1];
    const float* bq = (const float*)d_in[2];
    const float* Wk = (const float*)d_in[3];
    const float* bk = (const float*)d_in[4];
    const float* Wv = (const float*)d_in[5];
    const float* bv = (const float*)d_in[6];
    const float* Wo = (const float*)d_in[7];
    const float* bo = (const float*)d_in[8];
    float* out = (float*)d_out;

    char* ws = (char*)d_ws;
    unsigned short* xbf  = (unsigned short*)ws;
    unsigned short* wqkv = (unsigned short*)(ws + 8388608);
    unsigned short* wobf = (unsigned short*)(ws + 14680064);
    float*          bqkv = (float*)(ws + 16777216);
    unsigned short* Qb   = (unsigned short*)(ws + 16789504);
    unsigned short* Kb   = (unsigned short*)(ws + 16789504 + 8388608);
    unsigned short* Vtb  = (unsigned short*)(ws + 16789504 + 2 * 8388608);
    unsigned short* Ob   = (unsigned short*)(ws + 16789504 + 3 * 8388608);

    convert_all<<<8195, 256, 0, stream>>>(x, Wq, Wk, Wv, Wo, bq, bk, bv,
                                          xbf, wqkv, wobf, bqkv);
    gemm_bt<0, 128, 128, 2, 2><<<32 * 24, 256, 0, stream>>>(
        xbf, wqkv, bqkv, Qb, Kb, Vtb, nullptr, 32);
    attn_kernel<<<512, 256, 0, stream>>>(Qb, Kb, Vtb, Ob);
    gemm_bt<1, 64, 64, 2, 2><<<64 * 16, 256, 0, stream>>>(
        Ob, wobf, bo, nullptr, nullptr, nullptr, out, 64);
}